// Round 2
// baseline (625.990 us; speedup 1.0000x reference)
//
#include <hip/hip_runtime.h>
#include <hip/hip_bf16.h>
#include <cstdint>
#include <cstddef>

// Problem dims (fixed)
#define E_     16
#define H_     1024
#define D_     1024
#define T_     2048
#define TWO_D  2048
#define KFLAT  (E_ * D_)   // 16384

typedef float  f32x4  __attribute__((ext_vector_type(4)));
typedef short  bf16x8 __attribute__((ext_vector_type(8)));

static __device__ __forceinline__ unsigned short f2bf(float f) {
  union { float f; unsigned u; } v; v.f = f;
  unsigned u = v.u;
  unsigned r = (u + 0x7FFFu + ((u >> 16) & 1u)) >> 16;   // RNE
  return (unsigned short)r;
}

static __device__ __forceinline__ void gload16(const void* g, void* l) {
  __builtin_amdgcn_global_load_lds(
      (const __attribute__((address_space(1))) void*)g,
      (__attribute__((address_space(3))) void*)l, 16, 0, 0);
}

// ---------------------------------------------------------------------------
// T1: gate_up_proj [E][H][2D] f32  ->  Wg^T [E][D][H] bf16, Wu^T [E][D][H] bf16
//     (transpose + de-interleave even/odd columns + f32->bf16)
// grid (2D/64, H/64, E), 256 threads
__global__ void k_trans_gu(const float* __restrict__ gu,
                           unsigned short* __restrict__ wg,
                           unsigned short* __restrict__ wu) {
  __shared__ float tile[64][65];
  const int e  = blockIdx.z;
  const int h0 = blockIdx.y * 64;
  const int c0 = blockIdx.x * 64;
  const int tid = threadIdx.x;
  const float* src = gu + (size_t)e * H_ * TWO_D;
#pragma unroll
  for (int i = 0; i < 16; ++i) {
    int lin = tid + i * 256;
    int hr = lin >> 6, c = lin & 63;
    tile[hr][c] = src[(size_t)(h0 + hr) * TWO_D + c0 + c];
  }
  __syncthreads();
  const int d0 = c0 >> 1;
#pragma unroll
  for (int i = 0; i < 4; ++i) {           // gate (even cols)
    int lin = tid + i * 256;              // 0..1023
    int dg = lin >> 5, hp = lin & 31;
    int h = hp * 2;
    ushort2 o = make_ushort2(f2bf(tile[h][dg * 2]), f2bf(tile[h + 1][dg * 2]));
    *(ushort2*)&wg[(((size_t)e << 10) + d0 + dg) * H_ + h0 + h] = o;
  }
#pragma unroll
  for (int i = 0; i < 4; ++i) {           // up (odd cols)
    int lin = tid + i * 256;
    int dg = lin >> 5, hp = lin & 31;
    int h = hp * 2;
    ushort2 o = make_ushort2(f2bf(tile[h][dg * 2 + 1]), f2bf(tile[h + 1][dg * 2 + 1]));
    *(ushort2*)&wu[(((size_t)e << 10) + d0 + dg) * H_ + h0 + h] = o;
  }
}

// ---------------------------------------------------------------------------
// T2: down_proj [E][D][H] f32 -> Wd^T [H][E*D] bf16  (B^T for the fused GEMM2)
// grid (H/64, D/64, E), 256 threads
__global__ void k_trans_dn(const float* __restrict__ dn,
                           unsigned short* __restrict__ wd) {
  __shared__ float tile[64][65];
  const int e  = blockIdx.z;
  const int d0 = blockIdx.y * 64;
  const int h0 = blockIdx.x * 64;
  const int tid = threadIdx.x;
  const float* src = dn + (size_t)e * D_ * H_;
#pragma unroll
  for (int i = 0; i < 16; ++i) {
    int lin = tid + i * 256;
    int dr = lin >> 6, hc = lin & 63;
    tile[dr][hc] = src[(size_t)(d0 + dr) * H_ + h0 + hc];
  }
  __syncthreads();
#pragma unroll
  for (int i = 0; i < 8; ++i) {
    int lin = tid + i * 256;              // 0..2047
    int hr = lin >> 5, dp = lin & 31;
    ushort2 o = make_ushort2(f2bf(tile[dp * 2][hr]), f2bf(tile[dp * 2 + 1][hr]));
    *(ushort2*)&wd[(size_t)(h0 + hr) * KFLAT + (e << 10) + d0 + dp * 2] = o;
  }
}

// ---------------------------------------------------------------------------
// T3: hidden_states f32 -> bf16  (row-major [T][H])
__global__ void k_cvt_hs(const float* __restrict__ hs, unsigned short* __restrict__ hb) {
  int idx = blockIdx.x * blockDim.x + threadIdx.x;   // T_*H_/4 threads
  float4 v = ((const float4*)hs)[idx];
  ushort4 o;
  o.x = f2bf(v.x); o.y = f2bf(v.y); o.z = f2bf(v.z); o.w = f2bf(v.w);
  ((ushort4*)hb)[idx] = o;
}

// ---------------------------------------------------------------------------
// T4: out[t][h] = sum_e r[t,e] * down_bias[e][h]   (initializes d_out; GEMM2
//     atomically accumulates on top)
__global__ void k_bias_out(const float* __restrict__ rw, const float* __restrict__ db,
                           float* __restrict__ out) {
  int idx = blockIdx.x * blockDim.x + threadIdx.x;   // T_*H_
  int t = idx >> 10, h = idx & 1023;
  const float* r = rw + t * E_;
  float acc = 0.f;
#pragma unroll
  for (int e = 0; e < E_; ++e) acc += r[e] * db[(e << 10) + h];
  out[idx] = acc;
}

// ---------------------------------------------------------------------------
// GEMM1 (fused gate+up + activation + routing scale):
//   per expert e, tile 128 tokens x 64 act-cols (= 128 B-rows: 64 gate ; 64 up).
//   4 waves each own 32 token rows x all 128 B-rows, so each thread holds
//   matching gate/up accumulator fragments.
//   act[t][e*1024+d] = (clip(up)+1)*(min(gate,7)*sigmoid(1.702*min(gate,7))) * r[t,e]
// grid (D/64, T/128, E), 256 threads
__global__ void __launch_bounds__(256)
k_gemm1(const unsigned short* __restrict__ hb,
        const unsigned short* __restrict__ wg,
        const unsigned short* __restrict__ wu,
        const float* __restrict__ gub,
        const float* __restrict__ rw,
        unsigned short* __restrict__ act) {
  __shared__ __align__(16) short lsA[128 * 64];
  __shared__ __align__(16) short lsB[128 * 64];
  const int e  = blockIdx.z;
  const int t0 = blockIdx.y * 128;
  const int d0 = blockIdx.x * 64;
  const int tid  = threadIdx.x;
  const int lane = tid & 63;
  const int w    = tid >> 6;

  f32x4 acc[2][8];
#pragma unroll
  for (int mi = 0; mi < 2; ++mi)
#pragma unroll
    for (int nf = 0; nf < 8; ++nf) acc[mi][nf] = (f32x4)0.f;

  for (int kt = 0; kt < H_ / 64; ++kt) {
    const int k0 = kt * 64;
#pragma unroll
    for (int i = 0; i < 4; ++i) {         // stage A (tokens)
      int lin = tid + i * 256;
      int row = lin >> 3, ch = lin & 7;
      gload16(hb + (size_t)(t0 + row) * H_ + k0 + ch * 8, &lsA[lin * 8]);
    }
#pragma unroll
    for (int i = 0; i < 4; ++i) {         // stage B (gate rows then up rows)
      int lin = tid + i * 256;
      int row = lin >> 3, ch = lin & 7;
      const unsigned short* gb = (row < 64)
          ? wg + (((size_t)e << 10) + d0 + row) * H_ + k0 + ch * 8
          : wu + (((size_t)e << 10) + d0 + (row - 64)) * H_ + k0 + ch * 8;
      gload16(gb, &lsB[lin * 8]);
    }
    __syncthreads();
#pragma unroll
    for (int ks = 0; ks < 2; ++ks) {
      const int koff = ks * 32 + ((lane >> 4) << 3);
      bf16x8 af[2], bfr[8];
#pragma unroll
      for (int mi = 0; mi < 2; ++mi)
        af[mi] = *(const bf16x8*)&lsA[((w * 32 + mi * 16 + (lane & 15)) << 6) + koff];
#pragma unroll
      for (int nf = 0; nf < 8; ++nf)
        bfr[nf] = *(const bf16x8*)&lsB[((nf * 16 + (lane & 15)) << 6) + koff];
#pragma unroll
      for (int mi = 0; mi < 2; ++mi)
#pragma unroll
        for (int nf = 0; nf < 8; ++nf)
          acc[mi][nf] = __builtin_amdgcn_mfma_f32_16x16x32_bf16(af[mi], bfr[nf], acc[mi][nf], 0, 0, 0);
    }
    __syncthreads();
  }

  const int col = lane & 15;
#pragma unroll
  for (int mi = 0; mi < 2; ++mi) {
#pragma unroll
    for (int rr = 0; rr < 4; ++rr) {
      const int t = t0 + w * 32 + mi * 16 + ((lane >> 4) << 2) + rr;
      const float r = rw[t * E_ + e];
#pragma unroll
      for (int nf = 0; nf < 4; ++nf) {
        const int d = d0 + nf * 16 + col;
        float g = acc[mi][nf][rr]     + gub[e * TWO_D + 2 * d];
        float u = acc[mi][nf + 4][rr] + gub[e * TWO_D + 2 * d + 1];
        g = fminf(g, 7.0f);
        u = fminf(fmaxf(u, -7.0f), 7.0f);
        float glu = g / (1.0f + __expf(-1.702f * g));
        float a = (u + 1.0f) * glu * r;
        act[(size_t)t * KFLAT + (e << 10) + d] = f2bf(a);
      }
    }
  }
}

// ---------------------------------------------------------------------------
// GEMM2: out[T][H] += act[T][E*D] @ Wd^T[H][E*D]^T   (single long-K GEMM over
//        all experts; act already carries r[t,e]); split-K=4 via f32 atomics.
// grid (H/128, T/128, 4), 256 threads (4 waves, 2x2 of 64x64)
__global__ void __launch_bounds__(256)
k_gemm2(const unsigned short* __restrict__ act,
        const unsigned short* __restrict__ wd,
        float* __restrict__ out) {
  __shared__ __align__(16) short lsA[128 * 64];
  __shared__ __align__(16) short lsB[128 * 64];
  const int ks_blk = blockIdx.z;
  const int t0 = blockIdx.y * 128;
  const int h0 = blockIdx.x * 128;
  const int tid  = threadIdx.x;
  const int lane = tid & 63;
  const int w    = tid >> 6;
  const int wm = w >> 1, wn = w & 1;

  f32x4 acc[4][4];
#pragma unroll
  for (int mi = 0; mi < 4; ++mi)
#pragma unroll
    for (int nf = 0; nf < 4; ++nf) acc[mi][nf] = (f32x4)0.f;

  const int kbeg = ks_blk * (KFLAT / 4);
  for (int kt = 0; kt < (KFLAT / 4) / 64; ++kt) {
    const int k0 = kbeg + kt * 64;
#pragma unroll
    for (int i = 0; i < 4; ++i) {
      int lin = tid + i * 256;
      int row = lin >> 3, ch = lin & 7;
      gload16(act + (size_t)(t0 + row) * KFLAT + k0 + ch * 8, &lsA[lin * 8]);
    }
#pragma unroll
    for (int i = 0; i < 4; ++i) {
      int lin = tid + i * 256;
      int row = lin >> 3, ch = lin & 7;
      gload16(wd + (size_t)(h0 + row) * KFLAT + k0 + ch * 8, &lsB[lin * 8]);
    }
    __syncthreads();
#pragma unroll
    for (int ks = 0; ks < 2; ++ks) {
      const int koff = ks * 32 + ((lane >> 4) << 3);
      bf16x8 af[4], bfr[4];
#pragma unroll
      for (int mi = 0; mi < 4; ++mi)
        af[mi] = *(const bf16x8*)&lsA[((wm * 64 + mi * 16 + (lane & 15)) << 6) + koff];
#pragma unroll
      for (int nf = 0; nf < 4; ++nf)
        bfr[nf] = *(const bf16x8*)&lsB[((wn * 64 + nf * 16 + (lane & 15)) << 6) + koff];
#pragma unroll
      for (int mi = 0; mi < 4; ++mi)
#pragma unroll
        for (int nf = 0; nf < 4; ++nf)
          acc[mi][nf] = __builtin_amdgcn_mfma_f32_16x16x32_bf16(af[mi], bfr[nf], acc[mi][nf], 0, 0, 0);
    }
    __syncthreads();
  }

  const int col = lane & 15;
#pragma unroll
  for (int mi = 0; mi < 4; ++mi) {
#pragma unroll
    for (int rr = 0; rr < 4; ++rr) {
      const int t = t0 + wm * 64 + mi * 16 + ((lane >> 4) << 2) + rr;
#pragma unroll
      for (int nf = 0; nf < 4; ++nf) {
        const int h = h0 + wn * 64 + nf * 16 + col;
        atomicAdd(&out[(size_t)t * H_ + h], acc[mi][nf][rr]);
      }
    }
  }
}

// ---------------------------------------------------------------------------
extern "C" void kernel_launch(void* const* d_in, const int* in_sizes, int n_in,
                              void* d_out, int out_size, void* d_ws, size_t ws_size,
                              hipStream_t stream) {
  const float* hs  = (const float*)d_in[0];   // [1,2048,1024]
  const float* rw  = (const float*)d_in[1];   // [2048,16]
  const float* gup = (const float*)d_in[2];   // [16,1024,2048]
  const float* gub = (const float*)d_in[3];   // [16,2048]
  const float* dnp = (const float*)d_in[4];   // [16,1024,1024]
  const float* dnb = (const float*)d_in[5];   // [16,1024]
  float* out = (float*)d_out;                 // [2048*1024] f32

  // workspace layout (bytes): hb 4MB | wg 32MB | wu 32MB | wd 32MB | act 64MB
  char* ws = (char*)d_ws;
  unsigned short* hb  = (unsigned short*)(ws);
  unsigned short* wg  = (unsigned short*)(ws + (4UL   << 20));
  unsigned short* wu  = (unsigned short*)(ws + (36UL  << 20));
  unsigned short* wd  = (unsigned short*)(ws + (68UL  << 20));
  unsigned short* act = (unsigned short*)(ws + (100UL << 20));

  k_cvt_hs  <<<(T_ * H_ / 4) / 256, 256, 0, stream>>>(hs, hb);
  k_trans_gu<<<dim3(TWO_D / 64, H_ / 64, E_), 256, 0, stream>>>(gup, wg, wu);
  k_trans_dn<<<dim3(H_ / 64, D_ / 64, E_),    256, 0, stream>>>(dnp, wd);
  k_bias_out<<<(T_ * H_) / 256, 256, 0, stream>>>(rw, dnb, out);
  k_gemm1   <<<dim3(D_ / 64, T_ / 128, E_),   256, 0, stream>>>(hb, wg, wu, gub, rw, act);
  k_gemm2   <<<dim3(H_ / 128, T_ / 128, 4),   256, 0, stream>>>(act, wd, out);
}

// Round 3
// 573.683 us; speedup vs baseline: 1.0912x; 1.0912x over previous
//
#include <hip/hip_runtime.h>
#include <hip/hip_bf16.h>
#include <cstdint>
#include <cstddef>

// Problem dims (fixed)
#define E_     16
#define H_     1024
#define D_     1024
#define T_     2048
#define TWO_D  2048
#define KFLAT  (E_ * D_)   // 16384

typedef float  f32x4  __attribute__((ext_vector_type(4)));
typedef short  bf16x8 __attribute__((ext_vector_type(8)));

static __device__ __forceinline__ unsigned short f2bf(float f) {
  union { float f; unsigned u; } v; v.f = f;
  unsigned u = v.u;
  unsigned r = (u + 0x7FFFu + ((u >> 16) & 1u)) >> 16;   // RNE
  return (unsigned short)r;
}

static __device__ __forceinline__ void gload16(const void* g, void* l) {
  __builtin_amdgcn_global_load_lds(
      (const __attribute__((address_space(1))) void*)g,
      (__attribute__((address_space(3))) void*)l, 16, 0, 0);
}

// ---------------------------------------------------------------------------
// T1: gate_up_proj [E][H][2D] f32  ->  Wg^T [E][D][H] bf16, Wu^T [E][D][H] bf16
__global__ void k_trans_gu(const float* __restrict__ gu,
                           unsigned short* __restrict__ wg,
                           unsigned short* __restrict__ wu) {
  __shared__ float tile[64][65];
  const int e  = blockIdx.z;
  const int h0 = blockIdx.y * 64;
  const int c0 = blockIdx.x * 64;
  const int tid = threadIdx.x;
  const float* src = gu + (size_t)e * H_ * TWO_D;
#pragma unroll
  for (int i = 0; i < 16; ++i) {
    int lin = tid + i * 256;
    int hr = lin >> 6, c = lin & 63;
    tile[hr][c] = src[(size_t)(h0 + hr) * TWO_D + c0 + c];
  }
  __syncthreads();
  const int d0 = c0 >> 1;
#pragma unroll
  for (int i = 0; i < 4; ++i) {           // gate (even cols)
    int lin = tid + i * 256;
    int dg = lin >> 5, hp = lin & 31;
    int h = hp * 2;
    ushort2 o = make_ushort2(f2bf(tile[h][dg * 2]), f2bf(tile[h + 1][dg * 2]));
    *(ushort2*)&wg[(((size_t)e << 10) + d0 + dg) * H_ + h0 + h] = o;
  }
#pragma unroll
  for (int i = 0; i < 4; ++i) {           // up (odd cols)
    int lin = tid + i * 256;
    int dg = lin >> 5, hp = lin & 31;
    int h = hp * 2;
    ushort2 o = make_ushort2(f2bf(tile[h][dg * 2 + 1]), f2bf(tile[h + 1][dg * 2 + 1]));
    *(ushort2*)&wu[(((size_t)e << 10) + d0 + dg) * H_ + h0 + h] = o;
  }
}

// ---------------------------------------------------------------------------
// T2: down_proj [E][D][H] f32 -> Wd^T [H][E*D] bf16
__global__ void k_trans_dn(const float* __restrict__ dn,
                           unsigned short* __restrict__ wd) {
  __shared__ float tile[64][65];
  const int e  = blockIdx.z;
  const int d0 = blockIdx.y * 64;
  const int h0 = blockIdx.x * 64;
  const int tid = threadIdx.x;
  const float* src = dn + (size_t)e * D_ * H_;
#pragma unroll
  for (int i = 0; i < 16; ++i) {
    int lin = tid + i * 256;
    int dr = lin >> 6, hc = lin & 63;
    tile[dr][hc] = src[(size_t)(d0 + dr) * H_ + h0 + hc];
  }
  __syncthreads();
#pragma unroll
  for (int i = 0; i < 8; ++i) {
    int lin = tid + i * 256;
    int hr = lin >> 5, dp = lin & 31;
    ushort2 o = make_ushort2(f2bf(tile[dp * 2][hr]), f2bf(tile[dp * 2 + 1][hr]));
    *(ushort2*)&wd[(size_t)(h0 + hr) * KFLAT + (e << 10) + d0 + dp * 2] = o;
  }
}

// ---------------------------------------------------------------------------
// T3: hidden_states f32 -> bf16
__global__ void k_cvt_hs(const float* __restrict__ hs, unsigned short* __restrict__ hb) {
  int idx = blockIdx.x * blockDim.x + threadIdx.x;
  float4 v = ((const float4*)hs)[idx];
  ushort4 o;
  o.x = f2bf(v.x); o.y = f2bf(v.y); o.z = f2bf(v.z); o.w = f2bf(v.w);
  ((ushort4*)hb)[idx] = o;
}

// ---------------------------------------------------------------------------
// T4: out[t][h] = sum_e r[t,e] * down_bias[e][h]
__global__ void k_bias_out(const float* __restrict__ rw, const float* __restrict__ db,
                           float* __restrict__ out) {
  int idx = blockIdx.x * blockDim.x + threadIdx.x;
  int t = idx >> 10, h = idx & 1023;
  const float* r = rw + t * E_;
  float acc = 0.f;
#pragma unroll
  for (int e = 0; e < E_; ++e) acc += r[e] * db[(e << 10) + h];
  out[idx] = acc;
}

// ---------------------------------------------------------------------------
// GEMM1 (fused gate+up + activation + routing scale), double-buffered + swizzled.
//   Tile: 128 tokens x 64 d  (B-tile = 128 rows, gate/up interleaved per 16).
//   B-row r: type=(r>>4)&1 (0=gate,1=up), d_local=(r>>5)*16+(r&15).
//   Waves 2x2: wave (wm,wn) owns 64 tokens x 64 B-rows -> acc[4][4].
//   nf even = gate, nf odd = up for the same d  -> pairs in one thread.
// grid (D/64, T/128, E), 256 threads
__global__ void __launch_bounds__(256)
k_gemm1(const unsigned short* __restrict__ hb,
        const unsigned short* __restrict__ wg,
        const unsigned short* __restrict__ wu,
        const float* __restrict__ gub,
        const float* __restrict__ rw,
        unsigned short* __restrict__ act) {
  __shared__ __align__(16) short lsA[2][128 * 64];
  __shared__ __align__(16) short lsB[2][128 * 64];
  const int e  = blockIdx.z;
  const int t0 = blockIdx.y * 128;
  const int d0 = blockIdx.x * 64;
  const int tid  = threadIdx.x;
  const int lane = tid & 63;
  const int w    = tid >> 6;
  const int wm = w >> 1, wn = w & 1;
  const int lo = lane & 15, hi = lane >> 4;

  f32x4 acc[4][4];
#pragma unroll
  for (int mi = 0; mi < 4; ++mi)
#pragma unroll
    for (int nf = 0; nf < 4; ++nf) acc[mi][nf] = (f32x4)0.f;

#define G1_STAGE(buf, k0)                                                      \
  {                                                                            \
    _Pragma("unroll")                                                          \
    for (int i = 0; i < 4; ++i) {                                              \
      int lin = tid + i * 256; int row = lin >> 3, ch = lin & 7;               \
      int sch = ch ^ (row & 7);                                                \
      gload16(hb + (size_t)(t0 + row) * H_ + (k0) + sch * 8,                   \
              &lsA[buf][lin * 8]);                                             \
    }                                                                          \
    _Pragma("unroll")                                                          \
    for (int i = 0; i < 4; ++i) {                                              \
      int lin = tid + i * 256; int row = lin >> 3, ch = lin & 7;               \
      int sch = ch ^ (row & 7);                                                \
      int dl = ((row >> 5) << 4) + (row & 15);                                 \
      const unsigned short* bp = ((row >> 4) & 1) ? wu : wg;                   \
      gload16(bp + (((size_t)e << 10) + d0 + dl) * H_ + (k0) + sch * 8,        \
              &lsB[buf][lin * 8]);                                             \
    }                                                                          \
  }

  G1_STAGE(0, 0);
  __syncthreads();
  int cur = 0;
  for (int kt = 0; kt < H_ / 64; ++kt) {
    if (kt + 1 < H_ / 64) G1_STAGE(cur ^ 1, (kt + 1) * 64);
#pragma unroll
    for (int ks = 0; ks < 2; ++ks) {
      const int cb = (((ks << 2) | hi) ^ (lo & 7)) << 3;   // swizzled chunk (shorts)
      bf16x8 af[4], bfr[4];
#pragma unroll
      for (int mi = 0; mi < 4; ++mi)
        af[mi] = *(const bf16x8*)&lsA[cur][(wm * 64 + mi * 16 + lo) * 64 + cb];
#pragma unroll
      for (int nf = 0; nf < 4; ++nf)
        bfr[nf] = *(const bf16x8*)&lsB[cur][(wn * 64 + nf * 16 + lo) * 64 + cb];
#pragma unroll
      for (int mi = 0; mi < 4; ++mi)
#pragma unroll
        for (int nf = 0; nf < 4; ++nf)
          acc[mi][nf] = __builtin_amdgcn_mfma_f32_16x16x32_bf16(af[mi], bfr[nf], acc[mi][nf], 0, 0, 0);
    }
    __syncthreads();   // emits vmcnt(0)+lgkmcnt(0) drain; next iter flips buffers
    cur ^= 1;
  }
#undef G1_STAGE

#pragma unroll
  for (int mi = 0; mi < 4; ++mi) {
#pragma unroll
    for (int rr = 0; rr < 4; ++rr) {
      const int t = t0 + wm * 64 + mi * 16 + hi * 4 + rr;
      const float r = rw[t * E_ + e];
#pragma unroll
      for (int j = 0; j < 2; ++j) {
        const int d = d0 + wn * 32 + j * 16 + lo;
        float g = acc[mi][2 * j][rr]     + gub[e * TWO_D + 2 * d];
        float u = acc[mi][2 * j + 1][rr] + gub[e * TWO_D + 2 * d + 1];
        g = fminf(g, 7.0f);
        u = fminf(fmaxf(u, -7.0f), 7.0f);
        float glu = g / (1.0f + __expf(-1.702f * g));
        act[(size_t)t * KFLAT + (e << 10) + d] = f2bf((u + 1.0f) * glu * r);
      }
    }
  }
}

// ---------------------------------------------------------------------------
// GEMM2: out[T][H] += act[T][E*D] @ Wd^T[H][E*D]^T, split-K=4, dbuf + swizzle.
// grid (H/128, T/128, 4), 256 threads (2x2 waves, 64x64 each)
__global__ void __launch_bounds__(256)
k_gemm2(const unsigned short* __restrict__ act,
        const unsigned short* __restrict__ wd,
        float* __restrict__ out) {
  __shared__ __align__(16) short lsA[2][128 * 64];
  __shared__ __align__(16) short lsB[2][128 * 64];
  const int ks_blk = blockIdx.z;
  const int t0 = blockIdx.y * 128;
  const int h0 = blockIdx.x * 128;
  const int tid  = threadIdx.x;
  const int lane = tid & 63;
  const int w    = tid >> 6;
  const int wm = w >> 1, wn = w & 1;
  const int lo = lane & 15, hi = lane >> 4;

  f32x4 acc[4][4];
#pragma unroll
  for (int mi = 0; mi < 4; ++mi)
#pragma unroll
    for (int nf = 0; nf < 4; ++nf) acc[mi][nf] = (f32x4)0.f;

#define G2_STAGE(buf, k0)                                                      \
  {                                                                            \
    _Pragma("unroll")                                                          \
    for (int i = 0; i < 4; ++i) {                                              \
      int lin = tid + i * 256; int row = lin >> 3, ch = lin & 7;               \
      int sch = ch ^ (row & 7);                                                \
      gload16(act + (size_t)(t0 + row) * KFLAT + (k0) + sch * 8,               \
              &lsA[buf][lin * 8]);                                             \
    }                                                                          \
    _Pragma("unroll")                                                          \
    for (int i = 0; i < 4; ++i) {                                              \
      int lin = tid + i * 256; int row = lin >> 3, ch = lin & 7;               \
      int sch = ch ^ (row & 7);                                                \
      gload16(wd + (size_t)(h0 + row) * KFLAT + (k0) + sch * 8,                \
              &lsB[buf][lin * 8]);                                             \
    }                                                                          \
  }

  const int kbeg = ks_blk * (KFLAT / 4);
  const int NKT  = (KFLAT / 4) / 64;
  G2_STAGE(0, kbeg);
  __syncthreads();
  int cur = 0;
  for (int kt = 0; kt < NKT; ++kt) {
    if (kt + 1 < NKT) G2_STAGE(cur ^ 1, kbeg + (kt + 1) * 64);
#pragma unroll
    for (int ks = 0; ks < 2; ++ks) {
      const int cb = (((ks << 2) | hi) ^ (lo & 7)) << 3;
      bf16x8 af[4], bfr[4];
#pragma unroll
      for (int mi = 0; mi < 4; ++mi)
        af[mi] = *(const bf16x8*)&lsA[cur][(wm * 64 + mi * 16 + lo) * 64 + cb];
#pragma unroll
      for (int nf = 0; nf < 4; ++nf)
        bfr[nf] = *(const bf16x8*)&lsB[cur][(wn * 64 + nf * 16 + lo) * 64 + cb];
#pragma unroll
      for (int mi = 0; mi < 4; ++mi)
#pragma unroll
        for (int nf = 0; nf < 4; ++nf)
          acc[mi][nf] = __builtin_amdgcn_mfma_f32_16x16x32_bf16(af[mi], bfr[nf], acc[mi][nf], 0, 0, 0);
    }
    __syncthreads();
    cur ^= 1;
  }
#undef G2_STAGE

#pragma unroll
  for (int mi = 0; mi < 4; ++mi) {
#pragma unroll
    for (int rr = 0; rr < 4; ++rr) {
      const int t = t0 + wm * 64 + mi * 16 + hi * 4 + rr;
#pragma unroll
      for (int nf = 0; nf < 4; ++nf) {
        const int h = h0 + wn * 64 + nf * 16 + lo;
        atomicAdd(&out[(size_t)t * H_ + h], acc[mi][nf][rr]);
      }
    }
  }
}

// ---------------------------------------------------------------------------
extern "C" void kernel_launch(void* const* d_in, const int* in_sizes, int n_in,
                              void* d_out, int out_size, void* d_ws, size_t ws_size,
                              hipStream_t stream) {
  const float* hs  = (const float*)d_in[0];   // [1,2048,1024]
  const float* rw  = (const float*)d_in[1];   // [2048,16]
  const float* gup = (const float*)d_in[2];   // [16,1024,2048]
  const float* gub = (const float*)d_in[3];   // [16,2048]
  const float* dnp = (const float*)d_in[4];   // [16,1024,1024]
  const float* dnb = (const float*)d_in[5];   // [16,1024]
  float* out = (float*)d_out;                 // [2048*1024] f32

  // workspace layout (bytes): hb 4MB | wg 32MB | wu 32MB | wd 32MB | act 64MB
  char* ws = (char*)d_ws;
  unsigned short* hb  = (unsigned short*)(ws);
  unsigned short* wg  = (unsigned short*)(ws + (4UL   << 20));
  unsigned short* wu  = (unsigned short*)(ws + (36UL  << 20));
  unsigned short* wd  = (unsigned short*)(ws + (68UL  << 20));
  unsigned short* act = (unsigned short*)(ws + (100UL << 20));

  k_cvt_hs  <<<(T_ * H_ / 4) / 256, 256, 0, stream>>>(hs, hb);
  k_trans_gu<<<dim3(TWO_D / 64, H_ / 64, E_), 256, 0, stream>>>(gup, wg, wu);
  k_trans_dn<<<dim3(H_ / 64, D_ / 64, E_),    256, 0, stream>>>(dnp, wd);
  k_bias_out<<<(T_ * H_) / 256, 256, 0, stream>>>(rw, dnb, out);
  k_gemm1   <<<dim3(D_ / 64, T_ / 128, E_),   256, 0, stream>>>(hb, wg, wu, gub, rw, act);
  k_gemm2   <<<dim3(H_ / 128, T_ / 128, 4),   256, 0, stream>>>(act, wd, out);
}

// Round 5
// 531.486 us; speedup vs baseline: 1.1778x; 1.0794x over previous
//
#include <hip/hip_runtime.h>
#include <hip/hip_bf16.h>
#include <cstdint>
#include <cstddef>

// Problem dims (fixed)
#define E_     16
#define H_     1024
#define D_     1024
#define T_     2048
#define TWO_D  2048
#define KFLAT  (E_ * D_)   // 16384

typedef float  f32x4  __attribute__((ext_vector_type(4)));
typedef short  bf16x8 __attribute__((ext_vector_type(8)));

static __device__ __forceinline__ unsigned short f2bf(float f) {
  union { float f; unsigned u; } v; v.f = f;
  unsigned u = v.u;
  unsigned r = (u + 0x7FFFu + ((u >> 16) & 1u)) >> 16;   // RNE
  return (unsigned short)r;
}

static __device__ __forceinline__ void gload16(const void* g, void* l) {
  __builtin_amdgcn_global_load_lds(
      (const __attribute__((address_space(1))) void*)g,
      (__attribute__((address_space(3))) void*)l, 16, 0, 0);
}

// ---------------------------------------------------------------------------
// T1: gate_up_proj [E][H][2D] f32  ->  Wg^T [E][D][H] bf16, Wu^T [E][D][H] bf16
__global__ void k_trans_gu(const float* __restrict__ gu,
                           unsigned short* __restrict__ wg,
                           unsigned short* __restrict__ wu) {
  __shared__ float tile[64][65];
  const int e  = blockIdx.z;
  const int h0 = blockIdx.y * 64;
  const int c0 = blockIdx.x * 64;
  const int tid = threadIdx.x;
  const float* src = gu + (size_t)e * H_ * TWO_D;
#pragma unroll
  for (int i = 0; i < 16; ++i) {
    int lin = tid + i * 256;
    int hr = lin >> 6, c = lin & 63;
    tile[hr][c] = src[(size_t)(h0 + hr) * TWO_D + c0 + c];
  }
  __syncthreads();
  const int d0 = c0 >> 1;
#pragma unroll
  for (int i = 0; i < 4; ++i) {           // gate (even cols)
    int lin = tid + i * 256;
    int dg = lin >> 5, hp = lin & 31;
    int h = hp * 2;
    ushort2 o = make_ushort2(f2bf(tile[h][dg * 2]), f2bf(tile[h + 1][dg * 2]));
    *(ushort2*)&wg[(((size_t)e << 10) + d0 + dg) * H_ + h0 + h] = o;
  }
#pragma unroll
  for (int i = 0; i < 4; ++i) {           // up (odd cols)
    int lin = tid + i * 256;
    int dg = lin >> 5, hp = lin & 31;
    int h = hp * 2;
    ushort2 o = make_ushort2(f2bf(tile[h][dg * 2 + 1]), f2bf(tile[h + 1][dg * 2 + 1]));
    *(ushort2*)&wu[(((size_t)e << 10) + d0 + dg) * H_ + h0 + h] = o;
  }
}

// ---------------------------------------------------------------------------
// T2: down_proj [E][D][H] f32 -> Wd^T [H][E*D] bf16
__global__ void k_trans_dn(const float* __restrict__ dn,
                           unsigned short* __restrict__ wd) {
  __shared__ float tile[64][65];
  const int e  = blockIdx.z;
  const int d0 = blockIdx.y * 64;
  const int h0 = blockIdx.x * 64;
  const int tid = threadIdx.x;
  const float* src = dn + (size_t)e * D_ * H_;
#pragma unroll
  for (int i = 0; i < 16; ++i) {
    int lin = tid + i * 256;
    int dr = lin >> 6, hc = lin & 63;
    tile[dr][hc] = src[(size_t)(d0 + dr) * H_ + h0 + hc];
  }
  __syncthreads();
#pragma unroll
  for (int i = 0; i < 8; ++i) {
    int lin = tid + i * 256;
    int hr = lin >> 5, dp = lin & 31;
    ushort2 o = make_ushort2(f2bf(tile[dp * 2][hr]), f2bf(tile[dp * 2 + 1][hr]));
    *(ushort2*)&wd[(size_t)(h0 + hr) * KFLAT + (e << 10) + d0 + dp * 2] = o;
  }
}

// ---------------------------------------------------------------------------
// T3: hidden_states f32 -> bf16
__global__ void k_cvt_hs(const float* __restrict__ hs, unsigned short* __restrict__ hb) {
  int idx = blockIdx.x * blockDim.x + threadIdx.x;
  float4 v = ((const float4*)hs)[idx];
  ushort4 o;
  o.x = f2bf(v.x); o.y = f2bf(v.y); o.z = f2bf(v.z); o.w = f2bf(v.w);
  ((ushort4*)hb)[idx] = o;
}

// ---------------------------------------------------------------------------
// T4: out[t][h] = sum_e r[t,e] * down_bias[e][h]
__global__ void k_bias_out(const float* __restrict__ rw, const float* __restrict__ db,
                           float* __restrict__ out) {
  int idx = blockIdx.x * blockDim.x + threadIdx.x;
  int t = idx >> 10, h = idx & 1023;
  const float* r = rw + t * E_;
  float acc = 0.f;
#pragma unroll
  for (int e = 0; e < E_; ++e) acc += r[e] * db[(e << 10) + h];
  out[idx] = acc;
}

// ---------------------------------------------------------------------------
// GEMM1: 256x256 tile (256 tokens x 256 B-rows = 128 d), BK=64, 512 threads,
//        8 waves 2Mx4N, per-wave 128x64, acc[8][4].
//   Pipeline: STAGE(t+1); vmcnt(8); barrier; compute(t); barrier.
//   (counted vmcnt: tile-t loads are 1 full compute-phase old; never drain 0)
//   B-row r: type=(r>>4)&1 (0=gate,1=up), d_local=(r>>5)*16+(r&15).
// grid (2048/256=8 [N], 2048/256=8 [M], 16 [E]), 512 threads
__global__ void __launch_bounds__(512, 2)
k_gemm1(const unsigned short* __restrict__ hb,
        const unsigned short* __restrict__ wg,
        const unsigned short* __restrict__ wu,
        const float* __restrict__ gub,
        const float* __restrict__ rw,
        unsigned short* __restrict__ act) {
  __shared__ __align__(16) short lsA[2][256 * 64];
  __shared__ __align__(16) short lsB[2][256 * 64];
  const int e     = blockIdx.z;
  const int t0    = blockIdx.y * 256;
  const int d0blk = blockIdx.x * 128;
  const int tid  = threadIdx.x;
  const int lane = tid & 63;
  const int w    = tid >> 6;
  const int wm = w >> 2, wn = w & 3;
  const int lo = lane & 15, hi = lane >> 4;

  // --- precomputed staging sources (loop-invariant; add k0*2 bytes each tile)
  const unsigned short* aS[4];
  const unsigned short* bS[4];
  int ldst[4];
#pragma unroll
  for (int i = 0; i < 4; ++i) {
    int lin = tid + i * 512;            // 0..2047
    int row = lin >> 3, ch = lin & 7;
    int sch = ch ^ (row & 7);           // source pre-swizzle (dest stays linear)
    ldst[i] = lin * 8;
    aS[i] = hb + (size_t)(t0 + row) * H_ + sch * 8;
    int dl = ((row >> 5) << 4) + (row & 15);
    const unsigned short* bp = ((row >> 4) & 1) ? wu : wg;
    bS[i] = bp + (((size_t)e << 10) + d0blk + dl) * H_ + sch * 8;
  }

#define G1_STAGE(buf, k0)                                                      \
  {                                                                            \
    _Pragma("unroll")                                                          \
    for (int i = 0; i < 4; ++i) gload16(aS[i] + (k0), &lsA[buf][ldst[i]]);     \
    _Pragma("unroll")                                                          \
    for (int i = 0; i < 4; ++i) gload16(bS[i] + (k0), &lsB[buf][ldst[i]]);     \
  }

  f32x4 acc[8][4];
#pragma unroll
  for (int mi = 0; mi < 8; ++mi)
#pragma unroll
    for (int nf = 0; nf < 4; ++nf) acc[mi][nf] = (f32x4)0.f;

  // swizzled k-chunk byte offsets (in shorts) for kk=0,1
  const int cb0 = ((0 | hi) ^ (lo & 7)) << 3;
  const int cb1 = ((4 | hi) ^ (lo & 7)) << 3;
  const int arow = (wm * 128 + lo) * 64;   // + mi*16*64
  const int brow = (wn * 64 + lo) * 64;    // + nf*16*64

#define G1_COMPUTE(cur)                                                        \
  {                                                                            \
    bf16x8 bfr[4], af[4];                                                      \
    /* phase 0: kk=0, mi 0..3 */                                               \
    _Pragma("unroll")                                                          \
    for (int nf = 0; nf < 4; ++nf) bfr[nf] = *(const bf16x8*)&lsB[cur][brow + nf * 1024 + cb0]; \
    _Pragma("unroll")                                                          \
    for (int mi = 0; mi < 4; ++mi) af[mi] = *(const bf16x8*)&lsA[cur][arow + mi * 1024 + cb0];  \
    __builtin_amdgcn_s_setprio(1);                                             \
    _Pragma("unroll")                                                          \
    for (int mi = 0; mi < 4; ++mi)                                             \
      _Pragma("unroll")                                                        \
      for (int nf = 0; nf < 4; ++nf)                                           \
        acc[mi][nf] = __builtin_amdgcn_mfma_f32_16x16x32_bf16(af[mi], bfr[nf], acc[mi][nf], 0, 0, 0); \
    __builtin_amdgcn_s_setprio(0);                                             \
    /* phase 1: kk=0, mi 4..7 */                                               \
    _Pragma("unroll")                                                          \
    for (int mi = 0; mi < 4; ++mi) af[mi] = *(const bf16x8*)&lsA[cur][arow + (mi + 4) * 1024 + cb0]; \
    __builtin_amdgcn_s_setprio(1);                                             \
    _Pragma("unroll")                                                          \
    for (int mi = 0; mi < 4; ++mi)                                             \
      _Pragma("unroll")                                                        \
      for (int nf = 0; nf < 4; ++nf)                                           \
        acc[mi + 4][nf] = __builtin_amdgcn_mfma_f32_16x16x32_bf16(af[mi], bfr[nf], acc[mi + 4][nf], 0, 0, 0); \
    __builtin_amdgcn_s_setprio(0);                                             \
    /* phase 2: kk=1, mi 0..3 */                                               \
    _Pragma("unroll")                                                          \
    for (int nf = 0; nf < 4; ++nf) bfr[nf] = *(const bf16x8*)&lsB[cur][brow + nf * 1024 + cb1]; \
    _Pragma("unroll")                                                          \
    for (int mi = 0; mi < 4; ++mi) af[mi] = *(const bf16x8*)&lsA[cur][arow + mi * 1024 + cb1];  \
    __builtin_amdgcn_s_setprio(1);                                             \
    _Pragma("unroll")                                                          \
    for (int mi = 0; mi < 4; ++mi)                                             \
      _Pragma("unroll")                                                        \
      for (int nf = 0; nf < 4; ++nf)                                           \
        acc[mi][nf] = __builtin_amdgcn_mfma_f32_16x16x32_bf16(af[mi], bfr[nf], acc[mi][nf], 0, 0, 0); \
    __builtin_amdgcn_s_setprio(0);                                             \
    /* phase 3: kk=1, mi 4..7 */                                               \
    _Pragma("unroll")                                                          \
    for (int mi = 0; mi < 4; ++mi) af[mi] = *(const bf16x8*)&lsA[cur][arow + (mi + 4) * 1024 + cb1]; \
    __builtin_amdgcn_s_setprio(1);                                             \
    _Pragma("unroll")                                                          \
    for (int mi = 0; mi < 4; ++mi)                                             \
      _Pragma("unroll")                                                        \
      for (int nf = 0; nf < 4; ++nf)                                           \
        acc[mi + 4][nf] = __builtin_amdgcn_mfma_f32_16x16x32_bf16(af[mi], bfr[nf], acc[mi + 4][nf], 0, 0, 0); \
    __builtin_amdgcn_s_setprio(0);                                             \
  }

  G1_STAGE(0, 0);
  for (int kt = 0; kt < 15; ++kt) {
    const int cur = kt & 1;
    G1_STAGE(cur ^ 1, (kt + 1) * 64);
    // tile kt's 8 loads are the oldest of 16 outstanding -> vmcnt(8)
    asm volatile("s_waitcnt vmcnt(8)\n\ts_barrier" ::: "memory");
    G1_COMPUTE(cur);
    asm volatile("s_barrier" ::: "memory");   // protect buf overwrite next iter
  }
  asm volatile("s_waitcnt vmcnt(0)\n\ts_barrier" ::: "memory");
  G1_COMPUTE(1);
#undef G1_STAGE
#undef G1_COMPUTE

  // epilogue: bias + clips + glu + routing scale -> act bf16
  float gb[2], ub[2];
#pragma unroll
  for (int j = 0; j < 2; ++j) {
    const int d = d0blk + (wn * 2 + j) * 16 + lo;
    gb[j] = gub[e * TWO_D + 2 * d];
    ub[j] = gub[e * TWO_D + 2 * d + 1];
  }
#pragma unroll
  for (int mi = 0; mi < 8; ++mi) {
#pragma unroll
    for (int rr = 0; rr < 4; ++rr) {
      const int t = t0 + wm * 128 + mi * 16 + hi * 4 + rr;
      const float r = rw[t * E_ + e];
#pragma unroll
      for (int j = 0; j < 2; ++j) {
        const int d = d0blk + (wn * 2 + j) * 16 + lo;
        float g = acc[mi][2 * j][rr]     + gb[j];
        float u = acc[mi][2 * j + 1][rr] + ub[j];
        g = fminf(g, 7.0f);
        u = fminf(fmaxf(u, -7.0f), 7.0f);
        float glu = g / (1.0f + __expf(-1.702f * g));
        act[(size_t)t * KFLAT + (e << 10) + d] = f2bf((u + 1.0f) * glu * r);
      }
    }
  }
}

// ---------------------------------------------------------------------------
// GEMM2: out[T][H] += act[T][E*D] @ Wd^T[H][E*D]^T, split-K=4, dbuf + swizzle.
// (unchanged from round 3 — port the new pipeline here after gemm1 validates)
// grid (H/128, T/128, 4), 256 threads (2x2 waves, 64x64 each)
__global__ void __launch_bounds__(256)
k_gemm2(const unsigned short* __restrict__ act,
        const unsigned short* __restrict__ wd,
        float* __restrict__ out) {
  __shared__ __align__(16) short lsA[2][128 * 64];
  __shared__ __align__(16) short lsB[2][128 * 64];
  const int ks_blk = blockIdx.z;
  const int t0 = blockIdx.y * 128;
  const int h0 = blockIdx.x * 128;
  const int tid  = threadIdx.x;
  const int lane = tid & 63;
  const int w    = tid >> 6;
  const int wm = w >> 1, wn = w & 1;
  const int lo = lane & 15, hi = lane >> 4;

  f32x4 acc[4][4];
#pragma unroll
  for (int mi = 0; mi < 4; ++mi)
#pragma unroll
    for (int nf = 0; nf < 4; ++nf) acc[mi][nf] = (f32x4)0.f;

#define G2_STAGE(buf, k0)                                                      \
  {                                                                            \
    _Pragma("unroll")                                                          \
    for (int i = 0; i < 4; ++i) {                                              \
      int lin = tid + i * 256; int row = lin >> 3, ch = lin & 7;               \
      int sch = ch ^ (row & 7);                                                \
      gload16(act + (size_t)(t0 + row) * KFLAT + (k0) + sch * 8,               \
              &lsA[buf][lin * 8]);                                             \
    }                                                                          \
    _Pragma("unroll")                                                          \
    for (int i = 0; i < 4; ++i) {                                              \
      int lin = tid + i * 256; int row = lin >> 3, ch = lin & 7;               \
      int sch = ch ^ (row & 7);                                                \
      gload16(wd + (size_t)(h0 + row) * KFLAT + (k0) + sch * 8,                \
              &lsB[buf][lin * 8]);                                             \
    }                                                                          \
  }

  const int kbeg = ks_blk * (KFLAT / 4);
  const int NKT  = (KFLAT / 4) / 64;
  G2_STAGE(0, kbeg);
  __syncthreads();
  int cur = 0;
  for (int kt = 0; kt < NKT; ++kt) {
    if (kt + 1 < NKT) G2_STAGE(cur ^ 1, kbeg + (kt + 1) * 64);
#pragma unroll
    for (int ks = 0; ks < 2; ++ks) {
      const int cb = (((ks << 2) | hi) ^ (lo & 7)) << 3;
      bf16x8 af[4], bfr[4];
#pragma unroll
      for (int mi = 0; mi < 4; ++mi)
        af[mi] = *(const bf16x8*)&lsA[cur][(wm * 64 + mi * 16 + lo) * 64 + cb];
#pragma unroll
      for (int nf = 0; nf < 4; ++nf)
        bfr[nf] = *(const bf16x8*)&lsB[cur][(wn * 64 + nf * 16 + lo) * 64 + cb];
#pragma unroll
      for (int mi = 0; mi < 4; ++mi)
#pragma unroll
        for (int nf = 0; nf < 4; ++nf)
          acc[mi][nf] = __builtin_amdgcn_mfma_f32_16x16x32_bf16(af[mi], bfr[nf], acc[mi][nf], 0, 0, 0);
    }
    __syncthreads();
    cur ^= 1;
  }
#undef G2_STAGE

#pragma unroll
  for (int mi = 0; mi < 4; ++mi) {
#pragma unroll
    for (int rr = 0; rr < 4; ++rr) {
      const int t = t0 + wm * 64 + mi * 16 + hi * 4 + rr;
#pragma unroll
      for (int nf = 0; nf < 4; ++nf) {
        const int h = h0 + wn * 64 + nf * 16 + lo;
        atomicAdd(&out[(size_t)t * H_ + h], acc[mi][nf][rr]);
      }
    }
  }
}

// ---------------------------------------------------------------------------
extern "C" void kernel_launch(void* const* d_in, const int* in_sizes, int n_in,
                              void* d_out, int out_size, void* d_ws, size_t ws_size,
                              hipStream_t stream) {
  const float* hs  = (const float*)d_in[0];   // [1,2048,1024]
  const float* rw  = (const float*)d_in[1];   // [2048,16]
  const float* gup = (const float*)d_in[2];   // [16,1024,2048]
  const float* gub = (const float*)d_in[3];   // [16,2048]
  const float* dnp = (const float*)d_in[4];   // [16,1024,1024]
  const float* dnb = (const float*)d_in[5];   // [16,1024]
  float* out = (float*)d_out;                 // [2048*1024] f32

  // workspace layout (bytes): hb 4MB | wg 32MB | wu 32MB | wd 32MB | act 64MB
  char* ws = (char*)d_ws;
  unsigned short* hb  = (unsigned short*)(ws);
  unsigned short* wg  = (unsigned short*)(ws + (4UL   << 20));
  unsigned short* wu  = (unsigned short*)(ws + (36UL  << 20));
  unsigned short* wd  = (unsigned short*)(ws + (68UL  << 20));
  unsigned short* act = (unsigned short*)(ws + (100UL << 20));

  k_cvt_hs  <<<(T_ * H_ / 4) / 256, 256, 0, stream>>>(hs, hb);
  k_trans_gu<<<dim3(TWO_D / 64, H_ / 64, E_), 256, 0, stream>>>(gup, wg, wu);
  k_trans_dn<<<dim3(H_ / 64, D_ / 64, E_),    256, 0, stream>>>(dnp, wd);
  k_bias_out<<<(T_ * H_) / 256, 256, 0, stream>>>(rw, dnb, out);
  k_gemm1   <<<dim3(TWO_D / 256, T_ / 256, E_), 512, 0, stream>>>(hb, wg, wu, gub, rw, act);
  k_gemm2   <<<dim3(H_ / 128, T_ / 128, 4),   256, 0, stream>>>(act, wd, out);
}